// Round 4
// baseline (810.167 us; speedup 1.0000x reference)
//
#include <hip/hip_runtime.h>

#define MM 4096
#define KK 4096
#define NN 11008
#define NP8 (NN/8)
#define KTILES (KK/32)
#define LDA 40   // As leading dim (shorts): 32 k + 8 pad; 16B-aligned b128 rows
#define LDB 34   // Bs leading dim (shorts): 32 k + 2 pad; 17-bank stride (coprime w/ 32)

typedef __bf16 bf16x8 __attribute__((ext_vector_type(8)));
typedef float f32x4 __attribute__((ext_vector_type(4)));

__device__ __forceinline__ unsigned short b16(float a){
  union { __bf16 v; unsigned short u; } t;
  t.v = (__bf16)a;            // HW cvt, RNE
  return t.u;
}

__global__ __launch_bounds__(256, 3) void awq_gemm(
    const float* __restrict__ x,        // [M,K] fp32 (fp16 widened by harness)
    const int* __restrict__ qweight,    // [K,N/8] int32, AWQ nibble order
    const int* __restrict__ qzeros,     // [G,N/8] int32
    const float* __restrict__ scales,   // [G,N] fp32
    const float* __restrict__ bias,     // [N] fp32
    float* __restrict__ out)            // [M,N] fp32 ("else float*" harness rule)
{
  __shared__ __align__(16) unsigned short As[128*LDA];  // bf16 A tile
  __shared__ __align__(16) unsigned short Bs[128*LDB];  // bf16 W tile, transposed Bs[n][k]

  const int tid  = threadIdx.x;
  const int wid  = tid >> 6;
  const int lane = tid & 63;
  const int l16  = lane & 15;
  const int quad = lane >> 4;
  const int wm   = (wid >> 1) * 64;
  const int wn   = (wid & 1) * 64;
  const int m0   = blockIdx.y * 128;
  const int n0   = blockIdx.x * 128;
  const int c0   = blockIdx.x * 16;       // packed-col base (N/8 units)

  // A staging: thread -> (row ar + 32*i, float4 at k=kq*4); 8 lanes/row, coalesced
  const int ar = tid >> 3;                // 0..31
  const int kq = tid & 7;                 // 0..7
  const float* pax = x + (size_t)(m0 + ar)*KK + kq*4;

  // B staging: thread -> packed col bc, k-row pair (br0, br0+1)
  const int bc  = tid & 15;
  const int br0 = (tid >> 4) * 2;
  const int* pb = qweight + (size_t)br0*NP8 + c0 + bc;

  const int SH[8] = {0,16,4,20,8,24,12,28};   // 4*AWQ_ORDER[j]

  float sreg[8], treg[8];                 // per-group s and -(128+z)*s for this thread's 8 n's

  f32x4 acc[4][4];                        // bias pre-folded
  {
    float bv[4];
    #pragma unroll
    for (int ni=0;ni<4;ni++) bv[ni] = bias[n0 + wn + ni*16 + l16];
    #pragma unroll
    for (int mi=0;mi<4;mi++)
      #pragma unroll
      for (int ni=0;ni<4;ni++)
        acc[mi][ni] = (f32x4){bv[ni], bv[ni], bv[ni], bv[ni]};
  }

  #pragma unroll 1
  for (int kt = 0; kt < KTILES; ++kt) {
    // global loads (overlap with previous tile's MFMA)
    f32x4 av[4];
    #pragma unroll
    for (int i=0;i<4;i++) av[i] = *(const f32x4*)(pax + (size_t)i*32*KK);
    unsigned int q0 = (unsigned int)pb[0];
    unsigned int q1 = (unsigned int)pb[NP8];
    pax += 32; pb += (size_t)32*NP8;

    // per-group scale/zero refresh (group = 128 k-rows = 4 tiles)
    if ((kt & 3) == 0) {
      const int g = kt >> 2;
      const float* sp = scales + (size_t)g*NN + n0 + 8*bc;
      unsigned int qz = (unsigned int)qzeros[(size_t)g*NP8 + c0 + bc];
      #pragma unroll
      for (int j=0;j<8;j++){
        float s = sp[j];
        float z = (float)((qz >> SH[j]) & 0xFu);
        sreg[j] = s;
        treg[j] = -(128.0f + z) * s;
      }
    }

    __syncthreads();   // previous tile's LDS reads complete

    // A -> LDS (fp32 -> bf16)
    #pragma unroll
    for (int i=0;i<4;i++){
      union { unsigned short s[4]; uint2 u; } t;
      t.s[0]=b16(av[i][0]); t.s[1]=b16(av[i][1]);
      t.s[2]=b16(av[i][2]); t.s[3]=b16(av[i][3]);
      *(uint2*)(&As[(i*32 + ar)*LDA + kq*4]) = t.u;
    }

    // B dequant -> transposed LDS; bf16-bias trick: 0x4300|q == bf16(128+q),
    // nibble pairs (j, j+1) sit 16 bits apart in AWQ order -> 2 elems/extract
    {
      const unsigned int M4v = 0x000F000Fu, BBv = 0x43004300u;
      unsigned int ea[4], fa[4];
      ea[0] = ( q0        & M4v) | BBv;   // (128+q) for n=8bc+{0,1} (lo,hi)
      ea[1] = ((q0 >> 4 ) & M4v) | BBv;   // {2,3}
      ea[2] = ((q0 >> 8 ) & M4v) | BBv;   // {4,5}
      ea[3] = ((q0 >> 12) & M4v) | BBv;   // {6,7}
      fa[0] = ( q1        & M4v) | BBv;
      fa[1] = ((q1 >> 4 ) & M4v) | BBv;
      fa[2] = ((q1 >> 8 ) & M4v) | BBv;
      fa[3] = ((q1 >> 12) & M4v) | BBv;
      #pragma unroll
      for (int j=0;j<8;j++){
        float e = (j&1) ? __uint_as_float(ea[j>>1] & 0xFFFF0000u)
                        : __uint_as_float(ea[j>>1] << 16);
        float f = (j&1) ? __uint_as_float(fa[j>>1] & 0xFFFF0000u)
                        : __uint_as_float(fa[j>>1] << 16);
        float w0 = fmaf(e, sreg[j], treg[j]);   // k = br0
        float w1 = fmaf(f, sreg[j], treg[j]);   // k = br0+1
        union { unsigned short s[2]; unsigned int u; } t;
        t.s[0]=b16(w0); t.s[1]=b16(w1);
        *(unsigned int*)(&Bs[(8*bc + j)*LDB + br0]) = t.u;
      }
    }

    __syncthreads();

    // fragments + MFMA (m89/m91-verified layout triple)
    bf16x8 af[4], bfr[4];
    #pragma unroll
    for (int mi=0;mi<4;mi++){
      union { uint4 u; bf16x8 v; } t;
      t.u = *(const uint4*)(&As[(wm + mi*16 + l16)*LDA + quad*8]);
      af[mi] = t.v;
    }
    #pragma unroll
    for (int ni=0;ni<4;ni++){
      const unsigned int* bp = (const unsigned int*)(&Bs[(wn + ni*16 + l16)*LDB + quad*8]);
      union { unsigned int u[4]; bf16x8 v; } t;
      t.u[0]=bp[0]; t.u[1]=bp[1]; t.u[2]=bp[2]; t.u[3]=bp[3];
      bfr[ni] = t.v;
    }
    #pragma unroll
    for (int mi=0;mi<4;mi++)
      #pragma unroll
      for (int ni=0;ni<4;ni++)
        acc[mi][ni] = __builtin_amdgcn_mfma_f32_16x16x32_bf16(af[mi], bfr[ni], acc[mi][ni], 0, 0, 0);
  }

  // epilogue: C/D layout col=l16 (=n), row=quad*4+r (=m); fp32 stores
  #pragma unroll
  for (int mi=0;mi<4;mi++)
    #pragma unroll
    for (int ni=0;ni<4;ni++){
      const int n = n0 + wn + ni*16 + l16;
      #pragma unroll
      for (int r=0;r<4;r++){
        const int m = m0 + wm + mi*16 + quad*4 + r;
        out[(size_t)m*NN + n] = acc[mi][ni][r];
      }
    }
}

extern "C" void kernel_launch(void* const* d_in, const int* in_sizes, int n_in,
                              void* d_out, int out_size, void* d_ws, size_t ws_size,
                              hipStream_t stream) {
  const float* x  = (const float*)d_in[0];
  const int* qw   = (const int*)d_in[1];
  const int* qz   = (const int*)d_in[2];
  const float* sc = (const float*)d_in[3];
  const float* bi = (const float*)d_in[4];
  float* out = (float*)d_out;
  dim3 grid(NN/128, MM/128);   // (86, 32)
  awq_gemm<<<grid, dim3(256), 0, stream>>>(x, qw, qz, sc, bi, out);
}